// Round 2
// baseline (671.770 us; speedup 1.0000x reference)
//
#include <hip/hip_runtime.h>
#include <cstdint>
#include <cstddef>

// ---------------- preprocessing kernels ----------------

__global__ __launch_bounds__(256) void count_kernel(const int* __restrict__ dst,
                                                    int* __restrict__ counts, int e) {
  int i = blockIdx.x * 256 + threadIdx.x;
  if (i < e) atomicAdd(&counts[dst[i]], 1);
}

__global__ __launch_bounds__(256) void dinv_kernel(const int* __restrict__ counts,
                                                   float* __restrict__ dinv, int n) {
  int i = blockIdx.x * 256 + threadIdx.x;
  if (i < n) dinv[i] = rsqrtf((float)(counts[i] + 1));  // +1 = self loop
}

__global__ __launch_bounds__(256) void scan1_kernel(const int* __restrict__ counts,
                                                    int* __restrict__ bsum, int n) {
  __shared__ int lds[256];
  int tid = threadIdx.x;
  int i = blockIdx.x * 256 + tid;
  lds[tid] = (i < n) ? counts[i] : 0;
  __syncthreads();
  for (int off = 128; off > 0; off >>= 1) {
    if (tid < off) lds[tid] += lds[tid + off];
    __syncthreads();
  }
  if (tid == 0) bsum[blockIdx.x] = lds[0];
}

// exclusive scan of nb (<=256) block sums, in place
__global__ __launch_bounds__(256) void scan2_kernel(int* __restrict__ bsum, int nb) {
  __shared__ int lds[256];
  int tid = threadIdx.x;
  int v = (tid < nb) ? bsum[tid] : 0;
  lds[tid] = v;
  __syncthreads();
  for (int off = 1; off < 256; off <<= 1) {
    int t = (tid >= off) ? lds[tid - off] : 0;
    __syncthreads();
    lds[tid] += t;
    __syncthreads();
  }
  if (tid < nb) bsum[tid] = lds[tid] - v;  // exclusive
}

__global__ __launch_bounds__(256) void scan3_kernel(const int* __restrict__ counts,
                                                    const int* __restrict__ bsum,
                                                    int* __restrict__ offsets, int n) {
  __shared__ int lds[256];
  int tid = threadIdx.x;
  int i = blockIdx.x * 256 + tid;
  int v = (i < n) ? counts[i] : 0;
  lds[tid] = v;
  __syncthreads();
  for (int off = 1; off < 256; off <<= 1) {
    int t = (tid >= off) ? lds[tid - off] : 0;
    __syncthreads();
    lds[tid] += t;
    __syncthreads();
  }
  if (i < n) offsets[i] = bsum[blockIdx.x] + lds[tid] - v;  // exclusive offsets
}

// builds CSR by dst; afterwards offsets[v] == segment END (start = end - counts[v])
__global__ __launch_bounds__(256) void scatter_kernel(const int* __restrict__ src,
                                                      const int* __restrict__ dst,
                                                      const float* __restrict__ dinv,
                                                      int* __restrict__ offsets,
                                                      int* __restrict__ csr_src,
                                                      float* __restrict__ csr_w, int e) {
  int i = blockIdx.x * 256 + threadIdx.x;
  if (i < e) {
    int d = dst[i], s = src[i];
    int pos = atomicAdd(&offsets[d], 1);
    csr_src[pos] = s;
    csr_w[pos] = dinv[s] * dinv[d];
  }
}

// ---------------- GEMM: T[M x BN] = X[M x 128] @ W[128 x BN] ----------------

template <int BN>
__global__ __launch_bounds__(256) void gemm_kernel(const float* __restrict__ X,
                                                   const float* __restrict__ W,
                                                   float* __restrict__ T, int M) {
  constexpr int BM = 64, BK = 32, K = 128;
  constexpr int TCN = BN / 4;        // threads along cols (each does float4)
  constexpr int TRN = 256 / TCN;     // thread row groups
  constexpr int RPT = BM / TRN;      // rows per thread
  constexpr int XLD = BM * BK / (4 * 256);  // float4 x-loads per thread (=2)
  constexpr int WLD = BK * BN / (4 * 256);  // float4 w-loads per thread

  __shared__ float xs[BM][BK];
  __shared__ float ws[BK][BN];

  int tid = threadIdx.x;
  int tc = tid % TCN, tr = tid / TCN;
  int row0 = blockIdx.x * BM;

  float4 xr[XLD], wr[WLD];
  float acc[RPT][4];
#pragma unroll
  for (int r = 0; r < RPT; ++r)
#pragma unroll
    for (int j = 0; j < 4; ++j) acc[r][j] = 0.f;

  auto load = [&](int k0) {
#pragma unroll
    for (int u = 0; u < XLD; ++u) {
      int idx = tid + 256 * u;
      int rr = idx >> 3;   // BK/4 = 8 float4 per row
      int cc = idx & 7;
      int grow = row0 + rr;
      if (grow >= M) grow = M - 1;  // clamp (value unused for guarded rows)
      xr[u] = *(const float4*)&X[(size_t)grow * K + k0 + cc * 4];
    }
#pragma unroll
    for (int u = 0; u < WLD; ++u) {
      int idx = tid + 256 * u;
      int rr = idx / (BN / 4);
      int cc = idx % (BN / 4);
      wr[u] = *(const float4*)&W[(size_t)(k0 + rr) * BN + cc * 4];
    }
  };

  load(0);
  for (int c = 0; c < K / BK; ++c) {
    if (c > 0) __syncthreads();
#pragma unroll
    for (int u = 0; u < XLD; ++u) {
      int idx = tid + 256 * u;
      *(float4*)&xs[idx >> 3][(idx & 7) * 4] = xr[u];
    }
#pragma unroll
    for (int u = 0; u < WLD; ++u) {
      int idx = tid + 256 * u;
      *(float4*)&ws[idx / (BN / 4)][(idx % (BN / 4)) * 4] = wr[u];
    }
    __syncthreads();
    if (c < K / BK - 1) load((c + 1) * BK);
#pragma unroll
    for (int kk = 0; kk < BK; ++kk) {
      float4 bv = *(const float4*)&ws[kk][tc * 4];
#pragma unroll
      for (int r = 0; r < RPT; ++r) {
        float a = xs[tr + TRN * r][kk];
        acc[r][0] += a * bv.x;
        acc[r][1] += a * bv.y;
        acc[r][2] += a * bv.z;
        acc[r][3] += a * bv.w;
      }
    }
  }
#pragma unroll
  for (int r = 0; r < RPT; ++r) {
    int grow = row0 + tr + TRN * r;
    if (grow < M) {
      float4 o;
      o.x = acc[r][0]; o.y = acc[r][1]; o.z = acc[r][2]; o.w = acc[r][3];
      *(float4*)&T[(size_t)grow * BN + tc * 4] = o;
    }
  }
}

// ---------------- aggregation: O[v] = dinv[v]^2*T[v] + sum_in w*T[src] + b ----------------

template <int F, bool RELU>
__global__ __launch_bounds__(256) void agg_kernel(const float* __restrict__ T,
                                                  const int* __restrict__ csr_src,
                                                  const float* __restrict__ csr_w,
                                                  const int* __restrict__ offsets,
                                                  const int* __restrict__ counts,
                                                  const float* __restrict__ dinv,
                                                  const float* __restrict__ bias,
                                                  float* __restrict__ O, int n) {
  constexpr int L = F / 4;       // lanes per node (each lane: one float4)
  constexpr int NPB = 256 / L;   // nodes per block
  int tid = threadIdx.x;
  int lane = tid % L;
  int v = blockIdx.x * NPB + tid / L;
  if (v >= n) return;

  float dv = dinv[v];
  float sw = dv * dv;                 // self-loop weight
  float4 t = *(const float4*)&T[(size_t)v * F + lane * 4];
  float ax = sw * t.x, ay = sw * t.y, az = sw * t.z, aw = sw * t.w;

  int end = offsets[v];
  int start = end - counts[v];
  for (int i = start; i < end; ++i) {
    int s = csr_src[i];
    float w = csr_w[i];
    float4 u = *(const float4*)&T[(size_t)s * F + lane * 4];
    ax += w * u.x; ay += w * u.y; az += w * u.z; aw += w * u.w;
  }
  float4 bb = *(const float4*)&bias[lane * 4];
  ax += bb.x; ay += bb.y; az += bb.z; aw += bb.w;
  if (RELU) {
    ax = fmaxf(ax, 0.f); ay = fmaxf(ay, 0.f);
    az = fmaxf(az, 0.f); aw = fmaxf(aw, 0.f);
  }
  float4 o; o.x = ax; o.y = ay; o.z = az; o.w = aw;
  *(float4*)&O[(size_t)v * F + lane * 4] = o;
}

// ---------------- pooling + softmax ----------------

__global__ __launch_bounds__(256) void pool_kernel(const float* __restrict__ h3,
                                                   const int* __restrict__ batch,
                                                   float* __restrict__ pooled,
                                                   float* __restrict__ gcnt, int n) {
  int tid = threadIdx.x;
  int lane = tid & 63;
  int v = blockIdx.x * 4 + (tid >> 6);
  if (v >= n) return;
  int b = batch[v];
  atomicAdd(&pooled[b * 64 + lane], h3[(size_t)v * 64 + lane]);
  if (lane == 0) atomicAdd(&gcnt[b], 1.0f);
}

__global__ __launch_bounds__(64) void softmax_kernel(const float* __restrict__ pooled,
                                                     const float* __restrict__ gcnt,
                                                     float* __restrict__ out) {
  int g = blockIdx.x;
  int lane = threadIdx.x;
  float c = fmaxf(gcnt[g], 1.0f);
  float v = pooled[g * 64 + lane] / c;
  float m = v;
#pragma unroll
  for (int off = 32; off >= 1; off >>= 1) m = fmaxf(m, __shfl_xor(m, off));
  float e = expf(v - m);
  float s = e;
#pragma unroll
  for (int off = 32; off >= 1; off >>= 1) s += __shfl_xor(s, off);
  out[g * 64 + lane] = e / s;
}

// ---------------- launch ----------------

extern "C" void kernel_launch(void* const* d_in, const int* in_sizes, int n_in,
                              void* d_out, int out_size, void* d_ws, size_t ws_size,
                              hipStream_t stream) {
  const float* x  = (const float*)d_in[0];
  const int* edge = (const int*)d_in[1];
  const int* batch = (const int*)d_in[2];
  const float* W0 = (const float*)d_in[3];
  const float* b0 = (const float*)d_in[4];
  const float* W1 = (const float*)d_in[5];
  const float* b1 = (const float*)d_in[6];
  const float* W2 = (const float*)d_in[7];
  const float* b2 = (const float*)d_in[8];
  float* out = (float*)d_out;

  const int N = in_sizes[2];      // 50000 nodes (batch vector length)
  const int E = in_sizes[1] / 2;  // 600000 edges
  const int* esrc = edge;
  const int* edst = edge + E;

  char* p = (char*)d_ws;
  auto alloc = [&](size_t bytes) {
    char* r = p;
    p += (bytes + 255) & ~(size_t)255;
    return r;
  };
  int*   counts  = (int*)alloc((size_t)N * 4);
  int*   offsets = (int*)alloc((size_t)N * 4);
  float* dinv    = (float*)alloc((size_t)N * 4);
  int*   bsum    = (int*)alloc(256 * 4);
  int*   csr_src = (int*)alloc((size_t)E * 4);
  float* csr_w   = (float*)alloc((size_t)E * 4);
  float* bufA    = (float*)alloc((size_t)N * 128 * 4);
  float* bufB    = (float*)alloc((size_t)N * 128 * 4);
  float* pooled  = (float*)alloc(128 * 64 * 4);
  float* gcnt    = (float*)alloc(128 * 4);

  int nbN = (N + 255) / 256;  // 196 (<=256, required by scan2)
  int nbE = (E + 255) / 256;

  hipMemsetAsync(counts, 0, (size_t)N * 4, stream);
  hipMemsetAsync(pooled, 0, 128 * 64 * 4, stream);
  hipMemsetAsync(gcnt, 0, 128 * 4, stream);

  count_kernel<<<nbE, 256, 0, stream>>>(edst, counts, E);
  dinv_kernel<<<nbN, 256, 0, stream>>>(counts, dinv, N);
  scan1_kernel<<<nbN, 256, 0, stream>>>(counts, bsum, N);
  scan2_kernel<<<1, 256, 0, stream>>>(bsum, nbN);
  scan3_kernel<<<nbN, 256, 0, stream>>>(counts, bsum, offsets, N);
  scatter_kernel<<<nbE, 256, 0, stream>>>(esrc, edst, dinv, offsets, csr_src, csr_w, E);

  // layer 1: t = x @ W0 ; h1 = relu(A t + b0)
  gemm_kernel<128><<<(N + 63) / 64, 256, 0, stream>>>(x, W0, bufA, N);
  agg_kernel<128, true><<<(N + 7) / 8, 256, 0, stream>>>(bufA, csr_src, csr_w, offsets,
                                                         counts, dinv, b0, bufB, N);
  // layer 2
  gemm_kernel<128><<<(N + 63) / 64, 256, 0, stream>>>(bufB, W1, bufA, N);
  agg_kernel<128, true><<<(N + 7) / 8, 256, 0, stream>>>(bufA, csr_src, csr_w, offsets,
                                                         counts, dinv, b1, bufB, N);
  // layer 3 (64-wide, no relu)
  gemm_kernel<64><<<(N + 63) / 64, 256, 0, stream>>>(bufB, W2, bufA, N);
  agg_kernel<64, false><<<(N + 15) / 16, 256, 0, stream>>>(bufA, csr_src, csr_w, offsets,
                                                           counts, dinv, b2, bufB, N);

  // mean pool + softmax
  pool_kernel<<<(N + 3) / 4, 256, 0, stream>>>(bufB, batch, pooled, gcnt, N);
  softmax_kernel<<<128, 64, 0, stream>>>(pooled, gcnt, out);
}

// Round 7
// 404.516 us; speedup vs baseline: 1.6607x; 1.6607x over previous
//
#include <hip/hip_runtime.h>
#include <cstdint>
#include <cstddef>

// ---------------- preprocessing kernels ----------------

__global__ __launch_bounds__(256) void count_kernel(const int* __restrict__ dst,
                                                    int* __restrict__ counts, int e) {
  int i = blockIdx.x * 256 + threadIdx.x;
  if (i < e) atomicAdd(&counts[dst[i]], 1);
}

__global__ __launch_bounds__(256) void dinv_kernel(const int* __restrict__ counts,
                                                   float* __restrict__ dinv, int n) {
  int i = blockIdx.x * 256 + threadIdx.x;
  if (i < n) dinv[i] = rsqrtf((float)(counts[i] + 1));  // +1 = self loop
}

__global__ __launch_bounds__(256) void scan1_kernel(const int* __restrict__ counts,
                                                    int* __restrict__ bsum, int n) {
  __shared__ int lds[256];
  int tid = threadIdx.x;
  int i = blockIdx.x * 256 + tid;
  lds[tid] = (i < n) ? counts[i] : 0;
  __syncthreads();
  for (int off = 128; off > 0; off >>= 1) {
    if (tid < off) lds[tid] += lds[tid + off];
    __syncthreads();
  }
  if (tid == 0) bsum[blockIdx.x] = lds[0];
}

// exclusive scan of nb (<=256) block sums, in place
__global__ __launch_bounds__(256) void scan2_kernel(int* __restrict__ bsum, int nb) {
  __shared__ int lds[256];
  int tid = threadIdx.x;
  int v = (tid < nb) ? bsum[tid] : 0;
  lds[tid] = v;
  __syncthreads();
  for (int off = 1; off < 256; off <<= 1) {
    int t = (tid >= off) ? lds[tid - off] : 0;
    __syncthreads();
    lds[tid] += t;
    __syncthreads();
  }
  if (tid < nb) bsum[tid] = lds[tid] - v;  // exclusive
}

__global__ __launch_bounds__(256) void scan3_kernel(const int* __restrict__ counts,
                                                    const int* __restrict__ bsum,
                                                    int* __restrict__ offsets, int n) {
  __shared__ int lds[256];
  int tid = threadIdx.x;
  int i = blockIdx.x * 256 + tid;
  int v = (i < n) ? counts[i] : 0;
  lds[tid] = v;
  __syncthreads();
  for (int off = 1; off < 256; off <<= 1) {
    int t = (tid >= off) ? lds[tid - off] : 0;
    __syncthreads();
    lds[tid] += t;
    __syncthreads();
  }
  if (i < n) offsets[i] = bsum[blockIdx.x] + lds[tid] - v;  // exclusive offsets
}

// builds CSR by dst with (src, weight) packed as int2;
// afterwards offsets[v] == segment END (start = end - counts[v])
__global__ __launch_bounds__(256) void scatter_kernel(const int* __restrict__ src,
                                                      const int* __restrict__ dst,
                                                      const float* __restrict__ dinv,
                                                      int* __restrict__ offsets,
                                                      int2* __restrict__ csr_sw, int e) {
  int i = blockIdx.x * 256 + threadIdx.x;
  if (i < e) {
    int d = dst[i], s = src[i];
    int pos = atomicAdd(&offsets[d], 1);
    csr_sw[pos] = make_int2(s, __float_as_int(dinv[s] * dinv[d]));
  }
}

// ---------------- GEMM: T[M x BN] = X[M x 128] @ W[128 x BN] ----------------

template <int BN>
__global__ __launch_bounds__(256) void gemm_kernel(const float* __restrict__ X,
                                                   const float* __restrict__ W,
                                                   float* __restrict__ T, int M) {
  constexpr int BM = 64, BK = 32, K = 128;
  constexpr int TCN = BN / 4;        // threads along cols (each does float4)
  constexpr int TRN = 256 / TCN;     // thread row groups
  constexpr int RPT = BM / TRN;      // rows per thread
  constexpr int XLD = BM * BK / (4 * 256);  // float4 x-loads per thread (=2)
  constexpr int WLD = BK * BN / (4 * 256);  // float4 w-loads per thread

  __shared__ float xs[BM][BK];
  __shared__ float ws[BK][BN];

  int tid = threadIdx.x;
  int tc = tid % TCN, tr = tid / TCN;
  int row0 = blockIdx.x * BM;

  float4 xr[XLD], wr[WLD];
  float acc[RPT][4];
#pragma unroll
  for (int r = 0; r < RPT; ++r)
#pragma unroll
    for (int j = 0; j < 4; ++j) acc[r][j] = 0.f;

  auto load = [&](int k0) {
#pragma unroll
    for (int u = 0; u < XLD; ++u) {
      int idx = tid + 256 * u;
      int rr = idx >> 3;   // BK/4 = 8 float4 per row
      int cc = idx & 7;
      int grow = row0 + rr;
      if (grow >= M) grow = M - 1;  // clamp (value unused for guarded rows)
      xr[u] = *(const float4*)&X[(size_t)grow * K + k0 + cc * 4];
    }
#pragma unroll
    for (int u = 0; u < WLD; ++u) {
      int idx = tid + 256 * u;
      int rr = idx / (BN / 4);
      int cc = idx % (BN / 4);
      wr[u] = *(const float4*)&W[(size_t)(k0 + rr) * BN + cc * 4];
    }
  };

  load(0);
  for (int c = 0; c < K / BK; ++c) {
    if (c > 0) __syncthreads();
#pragma unroll
    for (int u = 0; u < XLD; ++u) {
      int idx = tid + 256 * u;
      *(float4*)&xs[idx >> 3][(idx & 7) * 4] = xr[u];
    }
#pragma unroll
    for (int u = 0; u < WLD; ++u) {
      int idx = tid + 256 * u;
      *(float4*)&ws[idx / (BN / 4)][(idx % (BN / 4)) * 4] = wr[u];
    }
    __syncthreads();
    if (c < K / BK - 1) load((c + 1) * BK);
#pragma unroll
    for (int kk = 0; kk < BK; ++kk) {
      float4 bv = *(const float4*)&ws[kk][tc * 4];
#pragma unroll
      for (int r = 0; r < RPT; ++r) {
        float a = xs[tr + TRN * r][kk];
        acc[r][0] += a * bv.x;
        acc[r][1] += a * bv.y;
        acc[r][2] += a * bv.z;
        acc[r][3] += a * bv.w;
      }
    }
  }
#pragma unroll
  for (int r = 0; r < RPT; ++r) {
    int grow = row0 + tr + TRN * r;
    if (grow < M) {
      float4 o;
      o.x = acc[r][0]; o.y = acc[r][1]; o.z = acc[r][2]; o.w = acc[r][3];
      *(float4*)&T[(size_t)grow * BN + tc * 4] = o;
    }
  }
}

// ---------------- aggregation: O[v] = dinv[v]^2*T[v] + sum_in w*T[src] + b ----------------
// 4-wide edge unroll keeps 4 independent gathers in flight (latency hiding);
// (src, w) packed in int2 so each edge costs one 8B broadcast load.

template <int F, bool RELU>
__global__ __launch_bounds__(256) void agg_kernel(const float* __restrict__ T,
                                                  const int2* __restrict__ csr_sw,
                                                  const int* __restrict__ offsets,
                                                  const int* __restrict__ counts,
                                                  const float* __restrict__ dinv,
                                                  const float* __restrict__ bias,
                                                  float* __restrict__ O, int n) {
  constexpr int L = F / 4;       // lanes per node (each lane: one float4)
  constexpr int NPB = 256 / L;   // nodes per block
  int tid = threadIdx.x;
  int lane = tid % L;
  int v = blockIdx.x * NPB + tid / L;
  if (v >= n) return;

  float dv = dinv[v];
  float sw = dv * dv;                 // self-loop weight
  float4 t = *(const float4*)&T[(size_t)v * F + lane * 4];
  float ax = sw * t.x, ay = sw * t.y, az = sw * t.z, aw = sw * t.w;

  int end = offsets[v];
  int i = end - counts[v];
  for (; i + 4 <= end; i += 4) {
    int2 p0 = csr_sw[i + 0];
    int2 p1 = csr_sw[i + 1];
    int2 p2 = csr_sw[i + 2];
    int2 p3 = csr_sw[i + 3];
    float4 u0 = *(const float4*)&T[(size_t)p0.x * F + lane * 4];
    float4 u1 = *(const float4*)&T[(size_t)p1.x * F + lane * 4];
    float4 u2 = *(const float4*)&T[(size_t)p2.x * F + lane * 4];
    float4 u3 = *(const float4*)&T[(size_t)p3.x * F + lane * 4];
    float w0 = __int_as_float(p0.y), w1 = __int_as_float(p1.y);
    float w2 = __int_as_float(p2.y), w3 = __int_as_float(p3.y);
    ax += w0 * u0.x; ay += w0 * u0.y; az += w0 * u0.z; aw += w0 * u0.w;
    ax += w1 * u1.x; ay += w1 * u1.y; az += w1 * u1.z; aw += w1 * u1.w;
    ax += w2 * u2.x; ay += w2 * u2.y; az += w2 * u2.z; aw += w2 * u2.w;
    ax += w3 * u3.x; ay += w3 * u3.y; az += w3 * u3.z; aw += w3 * u3.w;
  }
  for (; i < end; ++i) {
    int2 p = csr_sw[i];
    float w = __int_as_float(p.y);
    float4 u = *(const float4*)&T[(size_t)p.x * F + lane * 4];
    ax += w * u.x; ay += w * u.y; az += w * u.z; aw += w * u.w;
  }
  float4 bb = *(const float4*)&bias[lane * 4];
  ax += bb.x; ay += bb.y; az += bb.z; aw += bb.w;
  if (RELU) {
    ax = fmaxf(ax, 0.f); ay = fmaxf(ay, 0.f);
    az = fmaxf(az, 0.f); aw = fmaxf(aw, 0.f);
  }
  float4 o; o.x = ax; o.y = ay; o.z = az; o.w = aw;
  *(float4*)&O[(size_t)v * F + lane * 4] = o;
}

// ---------------- pooling + softmax ----------------

// segmented mean-pool: batch[] is SORTED, so each wave owns 64 contiguous
// nodes, accumulates per-lane in a register, and flushes to global only on
// batch-id change (or at span end). ~60K atomics total vs 3.2M naive.
__global__ __launch_bounds__(256) void pool_kernel(const float* __restrict__ h3,
                                                   const int* __restrict__ batch,
                                                   float* __restrict__ pooled,
                                                   float* __restrict__ gcnt, int n) {
  constexpr int NPW = 64;  // nodes per wave
  int lane = threadIdx.x & 63;
  int wave = threadIdx.x >> 6;
  int v0 = (blockIdx.x * 4 + wave) * NPW;
  if (v0 >= n) return;
  int vend = min(v0 + NPW, n);

  float acc = 0.f;
  int cnt = 0;
  int bcur = batch[v0];
  for (int v = v0; v < vend; ++v) {
    int b = batch[v];
    if (b != bcur) {
      atomicAdd(&pooled[bcur * 64 + lane], acc);
      if (lane == 0) atomicAdd(&gcnt[bcur], (float)cnt);
      acc = 0.f; cnt = 0; bcur = b;
    }
    acc += h3[(size_t)v * 64 + lane];
    ++cnt;
  }
  atomicAdd(&pooled[bcur * 64 + lane], acc);
  if (lane == 0) atomicAdd(&gcnt[bcur], (float)cnt);
}

__global__ __launch_bounds__(64) void softmax_kernel(const float* __restrict__ pooled,
                                                     const float* __restrict__ gcnt,
                                                     float* __restrict__ out) {
  int g = blockIdx.x;
  int lane = threadIdx.x;
  float c = fmaxf(gcnt[g], 1.0f);
  float v = pooled[g * 64 + lane] / c;
  float m = v;
#pragma unroll
  for (int off = 32; off >= 1; off >>= 1) m = fmaxf(m, __shfl_xor(m, off));
  float e = expf(v - m);
  float s = e;
#pragma unroll
  for (int off = 32; off >= 1; off >>= 1) s += __shfl_xor(s, off);
  out[g * 64 + lane] = e / s;
}

// ---------------- launch ----------------

extern "C" void kernel_launch(void* const* d_in, const int* in_sizes, int n_in,
                              void* d_out, int out_size, void* d_ws, size_t ws_size,
                              hipStream_t stream) {
  const float* x  = (const float*)d_in[0];
  const int* edge = (const int*)d_in[1];
  const int* batch = (const int*)d_in[2];
  const float* W0 = (const float*)d_in[3];
  const float* b0 = (const float*)d_in[4];
  const float* W1 = (const float*)d_in[5];
  const float* b1 = (const float*)d_in[6];
  const float* W2 = (const float*)d_in[7];
  const float* b2 = (const float*)d_in[8];
  float* out = (float*)d_out;

  const int N = in_sizes[2];      // 50000 nodes (batch vector length)
  const int E = in_sizes[1] / 2;  // 600000 edges
  const int* esrc = edge;
  const int* edst = edge + E;

  char* p = (char*)d_ws;
  auto alloc = [&](size_t bytes) {
    char* r = p;
    p += (bytes + 255) & ~(size_t)255;
    return r;
  };
  int*   counts  = (int*)alloc((size_t)N * 4);
  int*   offsets = (int*)alloc((size_t)N * 4);
  float* dinv    = (float*)alloc((size_t)N * 4);
  int*   bsum    = (int*)alloc(256 * 4);
  int2*  csr_sw  = (int2*)alloc((size_t)E * 8);
  float* bufA    = (float*)alloc((size_t)N * 128 * 4);
  float* bufB    = (float*)alloc((size_t)N * 128 * 4);
  float* pooled  = (float*)alloc(128 * 64 * 4);
  float* gcnt    = (float*)alloc(128 * 4);

  int nbN = (N + 255) / 256;  // 196 (<=256, required by scan2)
  int nbE = (E + 255) / 256;

  hipMemsetAsync(counts, 0, (size_t)N * 4, stream);
  hipMemsetAsync(pooled, 0, 128 * 64 * 4, stream);
  hipMemsetAsync(gcnt, 0, 128 * 4, stream);

  count_kernel<<<nbE, 256, 0, stream>>>(edst, counts, E);
  dinv_kernel<<<nbN, 256, 0, stream>>>(counts, dinv, N);
  scan1_kernel<<<nbN, 256, 0, stream>>>(counts, bsum, N);
  scan2_kernel<<<1, 256, 0, stream>>>(bsum, nbN);
  scan3_kernel<<<nbN, 256, 0, stream>>>(counts, bsum, offsets, N);
  scatter_kernel<<<nbE, 256, 0, stream>>>(esrc, edst, dinv, offsets, csr_sw, E);

  // layer 1: t = x @ W0 ; h1 = relu(A t + b0)
  gemm_kernel<128><<<(N + 63) / 64, 256, 0, stream>>>(x, W0, bufA, N);
  agg_kernel<128, true><<<(N + 7) / 8, 256, 0, stream>>>(bufA, csr_sw, offsets,
                                                         counts, dinv, b0, bufB, N);
  // layer 2
  gemm_kernel<128><<<(N + 63) / 64, 256, 0, stream>>>(bufB, W1, bufA, N);
  agg_kernel<128, true><<<(N + 7) / 8, 256, 0, stream>>>(bufA, csr_sw, offsets,
                                                         counts, dinv, b1, bufB, N);
  // layer 3 (64-wide, no relu)
  gemm_kernel<64><<<(N + 63) / 64, 256, 0, stream>>>(bufB, W2, bufA, N);
  agg_kernel<64, false><<<(N + 15) / 16, 256, 0, stream>>>(bufA, csr_sw, offsets,
                                                           counts, dinv, b2, bufB, N);

  // mean pool + softmax
  pool_kernel<<<(N + 255) / 256, 256, 0, stream>>>(bufB, batch, pooled, gcnt, N);
  softmax_kernel<<<128, 64, 0, stream>>>(pooled, gcnt, out);
}

// Round 9
// 374.573 us; speedup vs baseline: 1.7934x; 1.0799x over previous
//
#include <hip/hip_runtime.h>
#include <cstdint>
#include <cstddef>

// ---------------- preprocessing kernels ----------------

__global__ __launch_bounds__(256) void count_kernel(const int* __restrict__ dst,
                                                    int* __restrict__ counts, int e) {
  int i = blockIdx.x * 256 + threadIdx.x;
  if (i < e) atomicAdd(&counts[dst[i]], 1);
}

__global__ __launch_bounds__(256) void dinv_kernel(const int* __restrict__ counts,
                                                   float* __restrict__ dinv, int n) {
  int i = blockIdx.x * 256 + threadIdx.x;
  if (i < n) dinv[i] = rsqrtf((float)(counts[i] + 1));  // +1 = self loop
}

__global__ __launch_bounds__(256) void scan1_kernel(const int* __restrict__ counts,
                                                    int* __restrict__ bsum, int n) {
  __shared__ int lds[256];
  int tid = threadIdx.x;
  int i = blockIdx.x * 256 + tid;
  lds[tid] = (i < n) ? counts[i] : 0;
  __syncthreads();
  for (int off = 128; off > 0; off >>= 1) {
    if (tid < off) lds[tid] += lds[tid + off];
    __syncthreads();
  }
  if (tid == 0) bsum[blockIdx.x] = lds[0];
}

// exclusive scan of nb (<=256) block sums, in place
__global__ __launch_bounds__(256) void scan2_kernel(int* __restrict__ bsum, int nb) {
  __shared__ int lds[256];
  int tid = threadIdx.x;
  int v = (tid < nb) ? bsum[tid] : 0;
  lds[tid] = v;
  __syncthreads();
  for (int off = 1; off < 256; off <<= 1) {
    int t = (tid >= off) ? lds[tid - off] : 0;
    __syncthreads();
    lds[tid] += t;
    __syncthreads();
  }
  if (tid < nb) bsum[tid] = lds[tid] - v;  // exclusive
}

__global__ __launch_bounds__(256) void scan3_kernel(const int* __restrict__ counts,
                                                    const int* __restrict__ bsum,
                                                    int* __restrict__ offsets, int n) {
  __shared__ int lds[256];
  int tid = threadIdx.x;
  int i = blockIdx.x * 256 + tid;
  int v = (i < n) ? counts[i] : 0;
  lds[tid] = v;
  __syncthreads();
  for (int off = 1; off < 256; off <<= 1) {
    int t = (tid >= off) ? lds[tid - off] : 0;
    __syncthreads();
    lds[tid] += t;
    __syncthreads();
  }
  if (i < n) offsets[i] = bsum[blockIdx.x] + lds[tid] - v;  // exclusive offsets
}

// builds CSR by dst with (src, weight) packed as int2;
// afterwards offsets[v] == segment END (start = end - counts[v])
__global__ __launch_bounds__(256) void scatter_kernel(const int* __restrict__ src,
                                                      const int* __restrict__ dst,
                                                      const float* __restrict__ dinv,
                                                      int* __restrict__ offsets,
                                                      int2* __restrict__ csr_sw, int e) {
  int i = blockIdx.x * 256 + threadIdx.x;
  if (i < e) {
    int d = dst[i], s = src[i];
    int pos = atomicAdd(&offsets[d], 1);
    csr_sw[pos] = make_int2(s, __float_as_int(dinv[s] * dinv[d]));
  }
}

// ---------------- GEMM: T[M x BN] = X[M x 128] @ W[128 x BN] ----------------
// Full-K one-barrier design: stage X-tile TRANSPOSED (xs[K][BM]) + entire W
// (ws[K][BN]) in LDS once, then a barrier-free k-loop. Each thread owns a
// 4x4 register tile: per k only 2x ds_read_b128 for 16 FMAs (0.125 LDS/FMA).
// BM=32 -> grid 1563 blocks (more blocks/CU than old 782) and no K-tiling
// barriers; latency hidden by 16 independent FMA chains.

template <int BM, int BN>
__global__ __launch_bounds__(256) void gemm_kernel(const float* __restrict__ X,
                                                   const float* __restrict__ W,
                                                   float* __restrict__ T, int M) {
  constexpr int K = 128;
  static_assert(BM * BN == 4096, "4x4 tile x 256 threads");
  __shared__ float xs[K][BM];   // X^T tile
  __shared__ float ws[K][BN];   // full W

  int tid = threadIdx.x;
  int row0 = blockIdx.x * BM;

  // stage X^T: coalesced global reads (TPR consecutive lanes cover one row),
  // transposed LDS writes (one-time, small bank-conflict cost is fine)
  {
    constexpr int TPR = 256 / BM;   // threads per row
    int r = tid / TPR;
    int lw = tid % TPR;
    int grow = row0 + r;
    if (grow >= M) grow = M - 1;    // clamp; garbage rows guarded at store
    const float* xp = &X[(size_t)grow * K];
#pragma unroll
    for (int u = 0; u < K / (4 * TPR); ++u) {
      int k = (lw + u * TPR) * 4;
      float4 v = *(const float4*)&xp[k];
      xs[k + 0][r] = v.x;
      xs[k + 1][r] = v.y;
      xs[k + 2][r] = v.z;
      xs[k + 3][r] = v.w;
    }
  }
  // stage W: layout matches row-major, pure linear float4 copy
  {
    const float4* wsrc = (const float4*)W;
    float4* wdst = (float4*)&ws[0][0];
#pragma unroll
    for (int u = 0; u < (K * BN) / 1024; ++u)
      wdst[tid + u * 256] = wsrc[tid + u * 256];
  }
  __syncthreads();

  int r0 = (tid % (BM / 4)) * 4;
  int c0 = (tid / (BM / 4)) * 4;
  float acc[4][4];
#pragma unroll
  for (int i = 0; i < 4; ++i)
#pragma unroll
    for (int j = 0; j < 4; ++j) acc[i][j] = 0.f;

#pragma unroll 8
  for (int k = 0; k < K; ++k) {
    float4 a = *(const float4*)&xs[k][r0];
    float4 b = *(const float4*)&ws[k][c0];
    float av[4] = {a.x, a.y, a.z, a.w};
    float bv[4] = {b.x, b.y, b.z, b.w};
#pragma unroll
    for (int i = 0; i < 4; ++i)
#pragma unroll
      for (int j = 0; j < 4; ++j) acc[i][j] += av[i] * bv[j];
  }

#pragma unroll
  for (int i = 0; i < 4; ++i) {
    int grow = row0 + r0 + i;
    if (grow < M) {
      float4 o = {acc[i][0], acc[i][1], acc[i][2], acc[i][3]};
      *(float4*)&T[(size_t)grow * BN + c0] = o;
    }
  }
}

// ---------------- aggregation: O[v] = dinv[v]^2*T[v] + sum_in w*T[src] + b ----------------
// 4-wide edge unroll keeps 4 independent gathers in flight (latency hiding);
// (src, w) packed in int2 so each edge costs one 8B broadcast load.

template <int F, bool RELU>
__global__ __launch_bounds__(256) void agg_kernel(const float* __restrict__ T,
                                                  const int2* __restrict__ csr_sw,
                                                  const int* __restrict__ offsets,
                                                  const int* __restrict__ counts,
                                                  const float* __restrict__ dinv,
                                                  const float* __restrict__ bias,
                                                  float* __restrict__ O, int n) {
  constexpr int L = F / 4;       // lanes per node (each lane: one float4)
  constexpr int NPB = 256 / L;   // nodes per block
  int tid = threadIdx.x;
  int lane = tid % L;
  int v = blockIdx.x * NPB + tid / L;
  if (v >= n) return;

  float dv = dinv[v];
  float sw = dv * dv;                 // self-loop weight
  float4 t = *(const float4*)&T[(size_t)v * F + lane * 4];
  float ax = sw * t.x, ay = sw * t.y, az = sw * t.z, aw = sw * t.w;

  int end = offsets[v];
  int i = end - counts[v];
  for (; i + 4 <= end; i += 4) {
    int2 p0 = csr_sw[i + 0];
    int2 p1 = csr_sw[i + 1];
    int2 p2 = csr_sw[i + 2];
    int2 p3 = csr_sw[i + 3];
    float4 u0 = *(const float4*)&T[(size_t)p0.x * F + lane * 4];
    float4 u1 = *(const float4*)&T[(size_t)p1.x * F + lane * 4];
    float4 u2 = *(const float4*)&T[(size_t)p2.x * F + lane * 4];
    float4 u3 = *(const float4*)&T[(size_t)p3.x * F + lane * 4];
    float w0 = __int_as_float(p0.y), w1 = __int_as_float(p1.y);
    float w2 = __int_as_float(p2.y), w3 = __int_as_float(p3.y);
    ax += w0 * u0.x; ay += w0 * u0.y; az += w0 * u0.z; aw += w0 * u0.w;
    ax += w1 * u1.x; ay += w1 * u1.y; az += w1 * u1.z; aw += w1 * u1.w;
    ax += w2 * u2.x; ay += w2 * u2.y; az += w2 * u2.z; aw += w2 * u2.w;
    ax += w3 * u3.x; ay += w3 * u3.y; az += w3 * u3.z; aw += w3 * u3.w;
  }
  for (; i < end; ++i) {
    int2 p = csr_sw[i];
    float w = __int_as_float(p.y);
    float4 u = *(const float4*)&T[(size_t)p.x * F + lane * 4];
    ax += w * u.x; ay += w * u.y; az += w * u.z; aw += w * u.w;
  }
  float4 bb = *(const float4*)&bias[lane * 4];
  ax += bb.x; ay += bb.y; az += bb.z; aw += bb.w;
  if (RELU) {
    ax = fmaxf(ax, 0.f); ay = fmaxf(ay, 0.f);
    az = fmaxf(az, 0.f); aw = fmaxf(aw, 0.f);
  }
  float4 o; o.x = ax; o.y = ay; o.z = az; o.w = aw;
  *(float4*)&O[(size_t)v * F + lane * 4] = o;
}

// ---------------- pooling + softmax ----------------

// segmented mean-pool: batch[] is SORTED, so each wave owns 64 contiguous
// nodes, accumulates per-lane in a register, and flushes to global only on
// batch-id change (or at span end). ~60K atomics total vs 3.2M naive.
__global__ __launch_bounds__(256) void pool_kernel(const float* __restrict__ h3,
                                                   const int* __restrict__ batch,
                                                   float* __restrict__ pooled,
                                                   float* __restrict__ gcnt, int n) {
  constexpr int NPW = 64;  // nodes per wave
  int lane = threadIdx.x & 63;
  int wave = threadIdx.x >> 6;
  int v0 = (blockIdx.x * 4 + wave) * NPW;
  if (v0 >= n) return;
  int vend = min(v0 + NPW, n);

  float acc = 0.f;
  int cnt = 0;
  int bcur = batch[v0];
  for (int v = v0; v < vend; ++v) {
    int b = batch[v];
    if (b != bcur) {
      atomicAdd(&pooled[bcur * 64 + lane], acc);
      if (lane == 0) atomicAdd(&gcnt[bcur], (float)cnt);
      acc = 0.f; cnt = 0; bcur = b;
    }
    acc += h3[(size_t)v * 64 + lane];
    ++cnt;
  }
  atomicAdd(&pooled[bcur * 64 + lane], acc);
  if (lane == 0) atomicAdd(&gcnt[bcur], (float)cnt);
}

__global__ __launch_bounds__(64) void softmax_kernel(const float* __restrict__ pooled,
                                                     const float* __restrict__ gcnt,
                                                     float* __restrict__ out) {
  int g = blockIdx.x;
  int lane = threadIdx.x;
  float c = fmaxf(gcnt[g], 1.0f);
  float v = pooled[g * 64 + lane] / c;
  float m = v;
#pragma unroll
  for (int off = 32; off >= 1; off >>= 1) m = fmaxf(m, __shfl_xor(m, off));
  float e = expf(v - m);
  float s = e;
#pragma unroll
  for (int off = 32; off >= 1; off >>= 1) s += __shfl_xor(s, off);
  out[g * 64 + lane] = e / s;
}

// ---------------- launch ----------------

extern "C" void kernel_launch(void* const* d_in, const int* in_sizes, int n_in,
                              void* d_out, int out_size, void* d_ws, size_t ws_size,
                              hipStream_t stream) {
  const float* x  = (const float*)d_in[0];
  const int* edge = (const int*)d_in[1];
  const int* batch = (const int*)d_in[2];
  const float* W0 = (const float*)d_in[3];
  const float* b0 = (const float*)d_in[4];
  const float* W1 = (const float*)d_in[5];
  const float* b1 = (const float*)d_in[6];
  const float* W2 = (const float*)d_in[7];
  const float* b2 = (const float*)d_in[8];
  float* out = (float*)d_out;

  const int N = in_sizes[2];      // 50000 nodes (batch vector length)
  const int E = in_sizes[1] / 2;  // 600000 edges
  const int* esrc = edge;
  const int* edst = edge + E;

  char* p = (char*)d_ws;
  auto alloc = [&](size_t bytes) {
    char* r = p;
    p += (bytes + 255) & ~(size_t)255;
    return r;
  };
  int*   counts  = (int*)alloc((size_t)N * 4);
  int*   offsets = (int*)alloc((size_t)N * 4);
  float* dinv    = (float*)alloc((size_t)N * 4);
  int*   bsum    = (int*)alloc(256 * 4);
  int2*  csr_sw  = (int2*)alloc((size_t)E * 8);
  float* bufA    = (float*)alloc((size_t)N * 128 * 4);
  float* bufB    = (float*)alloc((size_t)N * 128 * 4);
  float* pooled  = (float*)alloc(128 * 64 * 4);
  float* gcnt    = (float*)alloc(128 * 4);

  int nbN = (N + 255) / 256;  // 196 (<=256, required by scan2)
  int nbE = (E + 255) / 256;

  hipMemsetAsync(counts, 0, (size_t)N * 4, stream);
  hipMemsetAsync(pooled, 0, 128 * 64 * 4, stream);
  hipMemsetAsync(gcnt, 0, 128 * 4, stream);

  count_kernel<<<nbE, 256, 0, stream>>>(edst, counts, E);
  dinv_kernel<<<nbN, 256, 0, stream>>>(counts, dinv, N);
  scan1_kernel<<<nbN, 256, 0, stream>>>(counts, bsum, N);
  scan2_kernel<<<1, 256, 0, stream>>>(bsum, nbN);
  scan3_kernel<<<nbN, 256, 0, stream>>>(counts, bsum, offsets, N);
  scatter_kernel<<<nbE, 256, 0, stream>>>(esrc, edst, dinv, offsets, csr_sw, E);

  // layer 1: t = x @ W0 ; h1 = relu(A t + b0)
  gemm_kernel<32, 128><<<(N + 31) / 32, 256, 0, stream>>>(x, W0, bufA, N);
  agg_kernel<128, true><<<(N + 7) / 8, 256, 0, stream>>>(bufA, csr_sw, offsets,
                                                         counts, dinv, b0, bufB, N);
  // layer 2
  gemm_kernel<32, 128><<<(N + 31) / 32, 256, 0, stream>>>(bufB, W1, bufA, N);
  agg_kernel<128, true><<<(N + 7) / 8, 256, 0, stream>>>(bufA, csr_sw, offsets,
                                                         counts, dinv, b1, bufB, N);
  // layer 3 (64-wide, no relu)
  gemm_kernel<64, 64><<<(N + 63) / 64, 256, 0, stream>>>(bufB, W2, bufA, N);
  agg_kernel<64, false><<<(N + 15) / 16, 256, 0, stream>>>(bufA, csr_sw, offsets,
                                                           counts, dinv, b2, bufB, N);

  // mean pool + softmax
  pool_kernel<<<(N + 255) / 256, 256, 0, stream>>>(bufB, batch, pooled, gcnt, N);
  softmax_kernel<<<128, 64, 0, stream>>>(pooled, gcnt, out);
}